// Round 4
// baseline (208.053 us; speedup 1.0000x reference)
//
#include <hip/hip_runtime.h>
#include <hip/hip_bf16.h>
#include <math.h>

// Problem constants
constexpr int cHW   = 4096;   // H*W
constexpr int cC    = 128;
constexpr int cNH   = 4;
constexpr int cDH   = 32;
constexpr float cEPS = 1e-5f;
// dh^-0.5 * log2(e): scores in log2 domain, softmax via exp2, fixed max=0
constexpr float cQS = 0.2550347805f;
constexpr int SPLIT = 8;

typedef short bh8 __attribute__((ext_vector_type(8)));   // 8 bf16 (4 VGPRs)
typedef float f4  __attribute__((ext_vector_type(4)));   // MFMA C/D

static __device__ __forceinline__ unsigned short f2bf(float f) {
  union { __hip_bfloat16 h; unsigned short u; } cv;
  cv.h = __float2bfloat16(f);
  return cv.u;
}
static __device__ __forceinline__ unsigned pack2bf(float a, float b) {
  return (unsigned)f2bf(a) | ((unsigned)f2bf(b) << 16);
}
static __device__ __forceinline__ float bflo(unsigned pk) {
  return __builtin_bit_cast(float, pk << 16);
}
static __device__ __forceinline__ float bfhi(unsigned pk) {
  return __builtin_bit_cast(float, pk & 0xffff0000u);
}

// ---------------- block reduce (sum of two values over 256 threads) -------
__device__ __forceinline__ void block_reduce2(float& a, float& b, float* sbuf) {
  #pragma unroll
  for (int off = 32; off > 0; off >>= 1) {
    a += __shfl_down(a, off, 64);
    b += __shfl_down(b, off, 64);
  }
  int wave = threadIdx.x >> 6;
  int lane = threadIdx.x & 63;
  if (lane == 0) { sbuf[wave] = a; sbuf[4 + wave] = b; }
  __syncthreads();
  if (threadIdx.x == 0) {
    sbuf[8] = sbuf[0] + sbuf[1] + sbuf[2] + sbuf[3];
    sbuf[9] = sbuf[4] + sbuf[5] + sbuf[6] + sbuf[7];
  }
  __syncthreads();
  a = sbuf[8];
  b = sbuf[9];
}

// ---------------- prep: GN1 stats partials + weight transpose/pack --------
// blocks 0..255: stats of x (part[bx] = {sum,sumsq} over 4096 elems)
// blocks 256..271: transpose+pack w_qkv / w_out to [d][c] bf16
__global__ __launch_bounds__(256)
void prep(const float* __restrict__ x, float* __restrict__ part,
          const float* __restrict__ wq, const float* __restrict__ wo,
          unsigned short* __restrict__ wqT, unsigned short* __restrict__ woT) {
  __shared__ float lds[32 * 133];
  int L = threadIdx.x;
  if (blockIdx.x < 256) {
    int ng = blockIdx.x >> 3, sl = blockIdx.x & 7;
    const float4* s4 = (const float4*)x;
    float s = 0.f, s2 = 0.f;
    #pragma unroll
    for (int i = 0; i < 4; i++) {
      int idx = i * 256 + L;
      int c = idx >> 7, tt = idx & 127;
      float4 v = s4[(size_t)(ng * 8 + c) * 1024 + sl * 128 + tt];
      s  += v.x + v.y + v.z + v.w;
      s2 += v.x*v.x + v.y*v.y + v.z*v.z + v.w*v.w;
    }
    block_reduce2(s, s2, lds);
    if (L == 0) { part[blockIdx.x * 2] = s; part[blockIdx.x * 2 + 1] = s2; }
  } else {
    int bx = blockIdx.x - 256;
    const float* src; unsigned short* dst; int W, d0;
    if (bx < 12) { src = wq; dst = wqT; W = 384; d0 = bx * 32; }
    else         { src = wo; dst = woT; W = 128; d0 = (bx - 12) * 32; }
    #pragma unroll
    for (int i = 0; i < 16; i++) {
      int c = i * 8 + (L >> 5), d = L & 31;
      lds[d * 133 + c] = src[(size_t)c * W + d0 + d];
    }
    __syncthreads();
    int d = L >> 3, ch = L & 7, c0 = ch * 16;
    unsigned pk[8];
    #pragma unroll
    for (int j = 0; j < 8; j++)
      pk[j] = pack2bf(lds[d * 133 + c0 + 2 * j], lds[d * 133 + c0 + 2 * j + 1]);
    uint4* d4 = (uint4*)(dst + (size_t)(d0 + d) * 128 + c0);
    d4[0] = make_uint4(pk[0], pk[1], pk[2], pk[3]);
    d4[1] = make_uint4(pk[4], pk[5], pk[6], pk[7]);
  }
}

// ---------------- GN1 apply + bf16 chunk pack -----------------------------
// xnB layout: [n][16 cc][4096 t][8 c] bf16
__global__ __launch_bounds__(256)
void gn1_pack(const float* __restrict__ x, const float* __restrict__ part,
              const float* __restrict__ sc, const float* __restrict__ of,
              unsigned short* __restrict__ xnB) {
  int cc = blockIdx.x, ts = blockIdx.y, n = blockIdx.z;
  int ng = n * 16 + cc;
  float s = 0.f, s2 = 0.f;
  #pragma unroll
  for (int p = 0; p < 8; p++) { s += part[(ng*8+p)*2]; s2 += part[(ng*8+p)*2+1]; }
  float mu = s * (1.0f / 32768.0f);
  float rinv = rsqrtf(s2 * (1.0f / 32768.0f) - mu * mu + cEPS);
  int t = ts * 256 + threadIdx.x;
  float v[8];
  #pragma unroll
  for (int j = 0; j < 8; j++) {
    int c = cc * 8 + j;
    float a = rinv * sc[c];
    float bo = of[c] - mu * a;
    v[j] = x[((size_t)n * cC + c) * cHW + t] * a + bo;
  }
  unsigned pk[4];
  #pragma unroll
  for (int j = 0; j < 4; j++) pk[j] = pack2bf(v[2*j], v[2*j+1]);
  ((uint4*)xnB)[(size_t)(n * 16 + cc) * cHW + t] = make_uint4(pk[0], pk[1], pk[2], pk[3]);
}

// ---------------- QKV projection (MFMA), A-frags held across dg loop ------
// grid (64 tt, 2 half, 2 n), block 256 (4 waves x 16 t-rows)
__global__ __launch_bounds__(256)
void qkv_mfma(const unsigned short* __restrict__ xnB, const unsigned short* __restrict__ wqT,
              const float* __restrict__ bq, unsigned* __restrict__ qB,
              unsigned* __restrict__ kB, unsigned* __restrict__ vI) {
  __shared__ float vbuf[64 * 36];
  const int L = threadIdx.x & 63, w = threadIdx.x >> 6;
  const int c16 = L & 15, q = L >> 4;
  const int t0 = blockIdx.x * 64, half = blockIdx.y, n = blockIdx.z;
  const f4 zf = {0.f, 0.f, 0.f, 0.f};
  const int trow = t0 + w * 16 + c16;
  bh8 a[4];
  #pragma unroll
  for (int ks = 0; ks < 4; ks++)
    a[ks] = *(const bh8*)(xnB + ((size_t)(n * 16 + ks * 4 + q) * cHW + trow) * 8);

  for (int dgi = 0; dgi < 6; dgi++) {
    int dg = half * 6 + dgi;
    int d0 = dg * 32, nh = n * 4 + (dg & 3);
    f4 acc0 = zf, acc1 = zf;
    #pragma unroll
    for (int ks = 0; ks < 4; ks++) {
      bh8 b0 = *(const bh8*)(wqT + (size_t)(d0 + c16) * 128 + ks * 32 + q * 8);
      bh8 b1 = *(const bh8*)(wqT + (size_t)(d0 + 16 + c16) * 128 + ks * 32 + q * 8);
      acc0 = __builtin_amdgcn_mfma_f32_16x16x32_bf16(a[ks], b0, acc0, 0, 0, 0);
      acc1 = __builtin_amdgcn_mfma_f32_16x16x32_bf16(a[ks], b1, acc1, 0, 0, 0);
    }
    float blo = bq[d0 + c16], bhi = bq[d0 + 16 + c16];
    if (dg < 8) {
      float scl = (dg < 4) ? cQS : 1.0f;
      unsigned* dst = (dg < 4) ? qB : kB;
      #pragma unroll
      for (int r = 0; r < 4; r++) {
        unsigned pk = pack2bf((acc0[r] + blo) * scl, (acc1[r] + bhi) * scl);
        dst[((size_t)nh * cHW + t0 + w * 16 + q * 4 + r) * 16 + c16] = pk;
      }
    } else {
      #pragma unroll
      for (int r = 0; r < 4; r++) {
        vbuf[(w * 16 + q * 4 + r) * 36 + c16]      = acc0[r] + blo;
        vbuf[(w * 16 + q * 4 + r) * 36 + 16 + c16] = acc1[r] + bhi;
      }
      __syncthreads();
      int t16 = threadIdx.x & 15, dh8 = (threadIdx.x >> 4) & 15;
      #pragma unroll
      for (int blk = 0; blk < 2; blk++)
        #pragma unroll
        for (int hh = 0; hh < 2; hh++) {
          int dh = dh8 + hh * 16;
          float lo = vbuf[(blk * 32 + t16) * 36 + dh];
          float hi = vbuf[(blk * 32 + 16 + t16) * 36 + dh];
          vI[((size_t)nh * 32 + dh) * 2048 + (size_t)(t0 / 32 + blk) * 16 + t16] = pack2bf(lo, hi);
        }
      __syncthreads();
    }
  }
}

// ---------------- flash attention tile helper -----------------------------
__device__ __forceinline__ void attn_tile(const bh8* qa, const bh8* kf, bh8* kfn,
                                          f4 o[2][2], float l_r[2][4], float* pbuf,
                                          const unsigned short* kb,
                                          const unsigned short* vb,
                                          int kt, int ktn, int c16, int q) {
  const f4 zf = {0.f, 0.f, 0.f, 0.f};
  f4 sf[2][4];
  #pragma unroll
  for (int rt = 0; rt < 2; rt++)
    #pragma unroll
    for (int s = 0; s < 4; s++)
      sf[rt][s] = __builtin_amdgcn_mfma_f32_16x16x32_bf16(qa[rt], kf[s], zf, 0, 0, 0);
  // prefetch next tile's K (ping-pong buffer)
  #pragma unroll
  for (int s = 0; s < 4; s++)
    kfn[s] = *(const bh8*)(kb + (size_t)(ktn + s*16 + c16) * cDH + q * 8);
  // current tile's V (latency hidden under exp/pack below)
  bh8 vf[2][2];
  #pragma unroll
  for (int ks = 0; ks < 2; ks++)
    #pragma unroll
    for (int dt = 0; dt < 2; dt++)
      vf[ks][dt] = *(const bh8*)(vb + (size_t)(dt*16 + c16) * cHW + kt + ks*32 + q*8);

  // softmax numerator: exp2(s), fixed max 0; accumulate l; pack P -> LDS
  #pragma unroll
  for (int rt = 0; rt < 2; rt++) {
    #pragma unroll
    for (int s = 0; s < 4; s++)
      #pragma unroll
      for (int r = 0; r < 4; r++)
        sf[rt][s][r] = __builtin_amdgcn_exp2f(sf[rt][s][r]);
    #pragma unroll
    for (int r = 0; r < 4; r++)
      l_r[rt][r] += (sf[rt][0][r] + sf[rt][1][r]) + (sf[rt][2][r] + sf[rt][3][r]);
    #pragma unroll
    for (int st = 0; st < 2; st++)
      #pragma unroll
      for (int r = 0; r < 4; r++) {
        unsigned pk = pack2bf(sf[rt][2*st][r], sf[rt][2*st+1][r]);
        pbuf[(rt*2 + st)*320 + (q*4 + r)*20 + c16] = __builtin_bit_cast(float, pk);
      }
  }
  // P (A-frag via LDS roundtrip) x V -> O  (in-wave LDS: compiler orders deps)
  #pragma unroll
  for (int rt = 0; rt < 2; rt++)
    #pragma unroll
    for (int st = 0; st < 2; st++) {
      bh8 pa = *(const bh8*)(pbuf + (rt*2 + st)*320 + c16*20 + q*4);
      #pragma unroll
      for (int dt = 0; dt < 2; dt++)
        o[rt][dt] = __builtin_amdgcn_mfma_f32_16x16x32_bf16(pa, vf[st][dt], o[rt][dt], 0, 0, 0);
    }
}

// ---------------- MFMA flash attention, no-max softmax (split-K) ----------
// block = 64 (1 wave), 32 q-rows/wave. grid (128, 8 nh, SPLIT)
__global__ __launch_bounds__(64)
void flash_mfma(const unsigned short* __restrict__ qB,
                const unsigned short* __restrict__ kB,
                const unsigned short* __restrict__ vI,
                unsigned* __restrict__ opart, float* __restrict__ lpart) {
  __shared__ float pbuf[4 * 16 * 20];
  const int L = threadIdx.x, c16 = L & 15, q = L >> 4;
  const int qt = blockIdx.x, nh = blockIdx.y, ph = blockIdx.z;
  const f4 zf = {0.f, 0.f, 0.f, 0.f};

  const unsigned short* qb = qB + ((size_t)nh * cHW + qt * 32) * cDH;
  bh8 qa[2];
  qa[0] = *(const bh8*)(qb + (size_t)c16 * cDH + q * 8);
  qa[1] = *(const bh8*)(qb + (size_t)(16 + c16) * cDH + q * 8);

  f4 o[2][2] = {{zf, zf}, {zf, zf}};
  float l_r[2][4] = {{0.f,0.f,0.f,0.f},{0.f,0.f,0.f,0.f}};

  const unsigned short* kb = kB + (size_t)nh * cHW * cDH;
  const unsigned short* vb = vI + (size_t)nh * cDH * cHW;

  const int kbeg = ph * (cHW / SPLIT);          // 512 keys per phase
  const int kend = kbeg + cHW / SPLIT;

  bh8 kfA[4], kfB[4];
  #pragma unroll
  for (int s = 0; s < 4; s++)
    kfA[s] = *(const bh8*)(kb + (size_t)(kbeg + s*16 + c16) * cDH + q * 8);

  for (int kt = kbeg; kt < kend; kt += 128) {
    attn_tile(qa, kfA, kfB, o, l_r, pbuf, kb, vb, kt, kt + 64, c16, q);
    int ktn = (kt + 128 < kend) ? (kt + 128) : kbeg;   // wrap: harmless reload
    attn_tile(qa, kfB, kfA, o, l_r, pbuf, kb, vb, kt + 64, ktn, c16, q);
  }

  size_t base_r = (size_t)ph * 32768 + (size_t)nh * cHW + (size_t)qt * 32;
  #pragma unroll
  for (int rt = 0; rt < 2; rt++)
    #pragma unroll
    for (int r = 0; r < 4; r++) {
      float lsum = l_r[rt][r];
      #pragma unroll
      for (int d = 1; d < 16; d <<= 1) lsum += __shfl_xor(lsum, d, 64);
      size_t rr = base_r + rt*16 + q*4 + r;
      if (c16 == 0) lpart[rr] = lsum;
      // bf16 pair (col c16, col 16+c16)
      opart[rr * 16 + c16] = pack2bf(o[rt][0][r], o[rt][1][r]);
    }
}

// ---------------- split-K combine -> yB bf16 [row][32] --------------------
// grid 128, block 256; one thread per row
__global__ __launch_bounds__(256)
void combine(const unsigned* __restrict__ opart, const float* __restrict__ lpart,
             unsigned* __restrict__ yB) {
  size_t r = (size_t)blockIdx.x * 256 + threadIdx.x;
  float l = 0.f;
  #pragma unroll
  for (int p = 0; p < SPLIT; p++) l += lpart[(size_t)p * 32768 + r];
  float e[32];
  #pragma unroll
  for (int j = 0; j < 32; j++) e[j] = 0.f;
  #pragma unroll
  for (int p = 0; p < SPLIT; p++) {
    const uint4* op = (const uint4*)(opart + ((size_t)p * 32768 + r) * 16);
    #pragma unroll
    for (int j = 0; j < 4; j++) {
      uint4 v = op[j];
      e[j*4+0] += bflo(v.x); e[16+j*4+0] += bfhi(v.x);
      e[j*4+1] += bflo(v.y); e[16+j*4+1] += bfhi(v.y);
      e[j*4+2] += bflo(v.z); e[16+j*4+2] += bfhi(v.z);
      e[j*4+3] += bflo(v.w); e[16+j*4+3] += bfhi(v.w);
    }
  }
  float inv = 1.0f / l;
  unsigned pk[16];
  #pragma unroll
  for (int m = 0; m < 16; m++) pk[m] = pack2bf(e[2*m] * inv, e[2*m+1] * inv);
  uint4* dst = (uint4*)(yB + r * 16);
  #pragma unroll
  for (int j = 0; j < 4; j++)
    dst[j] = make_uint4(pk[4*j], pk[4*j+1], pk[4*j+2], pk[4*j+3]);
}

// ---------------- out projection (MFMA) + fused GN2 stats -----------------
// grid (64 tt, 2 dpair, 2 n), block 256; loops 2 dg with A-frags resident
__global__ __launch_bounds__(256)
void out_mfma(const unsigned short* __restrict__ yB, const unsigned short* __restrict__ woT,
              const float* __restrict__ bo, float* __restrict__ proj,
              float* __restrict__ stats2) {
  __shared__ float obuf[64 * 36];
  const int L = threadIdx.x & 63, w = threadIdx.x >> 6;
  const int c16 = L & 15, q = L >> 4;
  const int t0 = blockIdx.x * 64, dp = blockIdx.y, n = blockIdx.z;
  const f4 zf = {0.f, 0.f, 0.f, 0.f};
  const int trow = t0 + w * 16 + c16;
  bh8 a[4];
  #pragma unroll
  for (int h = 0; h < 4; h++)
    a[h] = *(const bh8*)(yB + ((size_t)(n * 4 + h) * cHW + trow) * 32 + q * 8);

  for (int dgi = 0; dgi < 2; dgi++) {
    int d0 = (dp * 2 + dgi) * 32;
    f4 acc0 = zf, acc1 = zf;
    #pragma unroll
    for (int h = 0; h < 4; h++) {
      bh8 b0 = *(const bh8*)(woT + (size_t)(d0 + c16) * 128 + h * 32 + q * 8);
      bh8 b1 = *(const bh8*)(woT + (size_t)(d0 + 16 + c16) * 128 + h * 32 + q * 8);
      acc0 = __builtin_amdgcn_mfma_f32_16x16x32_bf16(a[h], b0, acc0, 0, 0, 0);
      acc1 = __builtin_amdgcn_mfma_f32_16x16x32_bf16(a[h], b1, acc1, 0, 0, 0);
    }
    float blo = bo[d0 + c16], bhi = bo[d0 + 16 + c16];
    float v0[4], v1[4];
    float sa = 0.f, sa2 = 0.f, sb = 0.f, sb2 = 0.f;
    #pragma unroll
    for (int r = 0; r < 4; r++) {
      v0[r] = acc0[r] + blo; v1[r] = acc1[r] + bhi;
      sa += v0[r]; sa2 += v0[r]*v0[r];
      sb += v1[r]; sb2 += v1[r]*v1[r];
    }
    // reduce over lanes differing in c16&7 (d=1,2,4) and q (d=16,32):
    // leaves lanes 0 (group d0/8) and 8 (group d0/8+1) holding totals
    #pragma unroll
    for (int d = 1; d < 64; d <<= 1) {
      if (d == 8) continue;
      sa += __shfl_xor(sa, d, 64);  sa2 += __shfl_xor(sa2, d, 64);
      sb += __shfl_xor(sb, d, 64);  sb2 += __shfl_xor(sb2, d, 64);
    }
    if ((L & 0x37) == 0) {
      int gofs = (L >> 3) & 1;
      int ngb = n * 16 + (d0 >> 3);
      atomicAdd(&stats2[(ngb + gofs) * 2],     sa);
      atomicAdd(&stats2[(ngb + gofs) * 2 + 1], sa2);
      atomicAdd(&stats2[(ngb + 2 + gofs) * 2],     sb);
      atomicAdd(&stats2[(ngb + 2 + gofs) * 2 + 1], sb2);
    }
    // transpose epilogue -> proj [n][c][t]
    #pragma unroll
    for (int r = 0; r < 4; r++) {
      obuf[(w * 16 + q * 4 + r) * 36 + c16]      = v0[r];
      obuf[(w * 16 + q * 4 + r) * 36 + 16 + c16] = v1[r];
    }
    __syncthreads();
    int t16 = threadIdx.x & 15, d8 = (threadIdx.x >> 4) & 15;
    #pragma unroll
    for (int tc = 0; tc < 4; tc++)
      #pragma unroll
      for (int hh = 0; hh < 2; hh++) {
        int d = d8 + hh * 16;
        proj[((size_t)n * cC + d0 + d) * cHW + t0 + tc * 16 + t16] =
            obuf[(tc * 16 + t16) * 36 + d];
      }
    __syncthreads();
  }
}

// ---------------- GN2 apply + residual (recomputes xn from x) -------------
__global__ __launch_bounds__(256)
void gn2_apply(const float* __restrict__ x, const float* __restrict__ proj,
               const float* __restrict__ p1, const float* __restrict__ p2,
               const float* __restrict__ s1, const float* __restrict__ o1,
               const float* __restrict__ s2, const float* __restrict__ o2,
               float* __restrict__ out) {
  int tid = blockIdx.x * 256 + threadIdx.x;
  int Cg = tid >> 8;
  int n = Cg >> 7, ch = Cg & 127, g = ch >> 3, ng = n * 16 + g;
  float sa = 0.f, sb = 0.f;
  #pragma unroll
  for (int p = 0; p < 8; p++) { sa += p1[(ng*8+p)*2]; sb += p1[(ng*8+p)*2+1]; }
  float ta = p2[ng*2], tb = p2[ng*2+1];
  float mu1 = sa * (1.0f/32768.0f);
  float ri1 = rsqrtf(sb * (1.0f/32768.0f) - mu1*mu1 + cEPS);
  float a1 = ri1 * s1[ch], b1 = o1[ch] - mu1 * a1;
  float mu2 = ta * (1.0f/32768.0f);
  float ri2 = rsqrtf(tb * (1.0f/32768.0f) - mu2*mu2 + cEPS);
  float a2 = ri2 * s2[ch], b2 = o2[ch] - mu2 * a2;
  const float4* x4 = (const float4*)x;
  const float4* pr4 = (const float4*)proj;
  float4* o4 = (float4*)out;
  #pragma unroll
  for (int i = 0; i < 4; i++) {
    size_t f = (size_t)tid * 4 + i;
    float4 xv = x4[f], pv = pr4[f];
    float4 r;
    r.x = xv.x * a1 + b1 + pv.x * a2 + b2;
    r.y = xv.y * a1 + b1 + pv.y * a2 + b2;
    r.z = xv.z * a1 + b1 + pv.z * a2 + b2;
    r.w = xv.w * a1 + b1 + pv.w * a2 + b2;
    o4[f] = r;
  }
}

// ---------------- launcher ------------------------------------------------
extern "C" void kernel_launch(void* const* d_in, const int* in_sizes, int n_in,
                              void* d_out, int out_size, void* d_ws, size_t ws_size,
                              hipStream_t stream) {
  const float* x     = (const float*)d_in[0];
  const float* w_qkv = (const float*)d_in[1];
  const float* b_qkv = (const float*)d_in[2];
  const float* w_out = (const float*)d_in[3];
  const float* b_out = (const float*)d_in[4];
  const float* g1s   = (const float*)d_in[5];
  const float* g1o   = (const float*)d_in[6];
  const float* g2s   = (const float*)d_in[7];
  const float* g2o   = (const float*)d_in[8];
  float* out = (float*)d_out;
  float* ws  = (float*)d_ws;

  const size_t MAP = (size_t)2 * cC * cHW;            // 1,048,576 elems
  float* proj    = ws;                                // 4 MB
  float* lpart   = proj + MAP;                        // SPLIT*32768 fl = 1 MB
  float* stats1  = lpart + (size_t)SPLIT * 32768;     // 512 fl
  float* stats2  = stats1 + 512;                      // 64 fl
  unsigned* opart = (unsigned*)(stats2 + 64);         // SPLIT*32768*16 u32 = 16 MB
  unsigned* qB   = opart + (size_t)SPLIT * 32768 * 16;  // 512K u32 = 2 MB
  unsigned* kB   = qB + MAP / 2;                      // 2 MB
  unsigned* vI   = kB + MAP / 2;                      // 2 MB
  unsigned* yB   = vI + MAP / 2;                      // 2 MB
  unsigned short* xnB = (unsigned short*)(yB + MAP / 2);  // 2 MB
  unsigned short* wqT = xnB + MAP;                    // 96 KB
  unsigned short* woT = wqT + 49152;                  // 32 KB

  hipMemsetAsync(stats2, 0, 64 * sizeof(float), stream);
  prep      <<<dim3(272),          256, 0, stream>>>(x, stats1, w_qkv, w_out, wqT, woT);
  gn1_pack  <<<dim3(16, 16, 2),    256, 0, stream>>>(x, stats1, g1s, g1o, xnB);
  qkv_mfma  <<<dim3(64, 2, 2),     256, 0, stream>>>(xnB, wqT, b_qkv, qB, kB, vI);
  flash_mfma<<<dim3(128, 8, SPLIT), 64, 0, stream>>>((const unsigned short*)qB,
                                                     (const unsigned short*)kB,
                                                     (const unsigned short*)vI,
                                                     opart, lpart);
  combine   <<<dim3(128),          256, 0, stream>>>(opart, lpart, yB);
  out_mfma  <<<dim3(64, 2, 2),     256, 0, stream>>>((const unsigned short*)yB, woT,
                                                     b_out, proj, stats2);
  gn2_apply <<<dim3(256),          256, 0, stream>>>(x, proj, stats1, stats2,
                                                     g1s, g1o, g2s, g2o, out);
}

// Round 5
// 148.294 us; speedup vs baseline: 1.4030x; 1.4030x over previous
//
#include <hip/hip_runtime.h>
#include <hip/hip_bf16.h>
#include <math.h>

// Problem constants
constexpr int cHW   = 4096;   // H*W
constexpr int cC    = 128;
constexpr int cNH   = 4;
constexpr int cDH   = 32;
constexpr float cEPS = 1e-5f;
// dh^-0.5 * log2(e): scores in log2 domain, softmax via exp2, fixed max=0
constexpr float cQS = 0.2550347805f;
constexpr int SPLIT = 4;

typedef short bh8 __attribute__((ext_vector_type(8)));   // 8 bf16 (4 VGPRs)
typedef float f4  __attribute__((ext_vector_type(4)));   // MFMA C/D

static __device__ __forceinline__ unsigned short f2bf(float f) {
  union { __hip_bfloat16 h; unsigned short u; } cv;
  cv.h = __float2bfloat16(f);
  return cv.u;
}
static __device__ __forceinline__ unsigned pack2bf(float a, float b) {
  return (unsigned)f2bf(a) | ((unsigned)f2bf(b) << 16);
}
// truncating pack: 2 VALU (lshr + and_or). Error cancels in softmax since
// l is computed from the same truncated P via MFMA-with-ones.
static __device__ __forceinline__ unsigned pack_trunc(float a, float b) {
  unsigned ua = __builtin_bit_cast(unsigned, a);
  unsigned ub = __builtin_bit_cast(unsigned, b);
  return (ua >> 16) | (ub & 0xffff0000u);
}
static __device__ __forceinline__ float bflo(unsigned pk) {
  return __builtin_bit_cast(float, pk << 16);
}
static __device__ __forceinline__ float bfhi(unsigned pk) {
  return __builtin_bit_cast(float, pk & 0xffff0000u);
}

// ---------------- block reduce (sum of two values over 256 threads) -------
__device__ __forceinline__ void block_reduce2(float& a, float& b, float* sbuf) {
  #pragma unroll
  for (int off = 32; off > 0; off >>= 1) {
    a += __shfl_down(a, off, 64);
    b += __shfl_down(b, off, 64);
  }
  int wave = threadIdx.x >> 6;
  int lane = threadIdx.x & 63;
  if (lane == 0) { sbuf[wave] = a; sbuf[4 + wave] = b; }
  __syncthreads();
  if (threadIdx.x == 0) {
    sbuf[8] = sbuf[0] + sbuf[1] + sbuf[2] + sbuf[3];
    sbuf[9] = sbuf[4] + sbuf[5] + sbuf[6] + sbuf[7];
  }
  __syncthreads();
  a = sbuf[8];
  b = sbuf[9];
}

// ---------------- prep: GN1 stats partials + weight transpose/pack --------
// blocks 0..255: stats of x; blocks 256..271: pack w_qkv / w_out to [d][c] bf16
__global__ __launch_bounds__(256)
void prep(const float* __restrict__ x, float* __restrict__ part,
          const float* __restrict__ wq, const float* __restrict__ wo,
          unsigned short* __restrict__ wqT, unsigned short* __restrict__ woT) {
  __shared__ float lds[32 * 133];
  int L = threadIdx.x;
  if (blockIdx.x < 256) {
    int ng = blockIdx.x >> 3, sl = blockIdx.x & 7;
    const float4* s4 = (const float4*)x;
    float s = 0.f, s2 = 0.f;
    #pragma unroll
    for (int i = 0; i < 4; i++) {
      int idx = i * 256 + L;
      int c = idx >> 7, tt = idx & 127;
      float4 v = s4[(size_t)(ng * 8 + c) * 1024 + sl * 128 + tt];
      s  += v.x + v.y + v.z + v.w;
      s2 += v.x*v.x + v.y*v.y + v.z*v.z + v.w*v.w;
    }
    block_reduce2(s, s2, lds);
    if (L == 0) { part[blockIdx.x * 2] = s; part[blockIdx.x * 2 + 1] = s2; }
  } else {
    int bx = blockIdx.x - 256;
    const float* src; unsigned short* dst; int W, d0;
    if (bx < 12) { src = wq; dst = wqT; W = 384; d0 = bx * 32; }
    else         { src = wo; dst = woT; W = 128; d0 = (bx - 12) * 32; }
    #pragma unroll
    for (int i = 0; i < 16; i++) {
      int c = i * 8 + (L >> 5), d = L & 31;
      lds[d * 133 + c] = src[(size_t)c * W + d0 + d];
    }
    __syncthreads();
    int d = L >> 3, ch = L & 7, c0 = ch * 16;
    unsigned pk[8];
    #pragma unroll
    for (int j = 0; j < 8; j++)
      pk[j] = pack2bf(lds[d * 133 + c0 + 2 * j], lds[d * 133 + c0 + 2 * j + 1]);
    uint4* d4 = (uint4*)(dst + (size_t)(d0 + d) * 128 + c0);
    d4[0] = make_uint4(pk[0], pk[1], pk[2], pk[3]);
    d4[1] = make_uint4(pk[4], pk[5], pk[6], pk[7]);
  }
}

// ---------------- GN stats partials (standalone, for proj) ----------------
__global__ __launch_bounds__(256)
void gn_stats(const float* __restrict__ src, float* __restrict__ part) {
  __shared__ float sbuf[10];
  int ng = blockIdx.x >> 3, sl = blockIdx.x & 7;
  const float4* s4 = (const float4*)src;
  float s = 0.f, s2 = 0.f;
  #pragma unroll
  for (int i = 0; i < 4; i++) {
    int idx = i * 256 + threadIdx.x;
    int c = idx >> 7, tt = idx & 127;
    float4 v = s4[(size_t)(ng * 8 + c) * 1024 + sl * 128 + tt];
    s  += v.x + v.y + v.z + v.w;
    s2 += v.x*v.x + v.y*v.y + v.z*v.z + v.w*v.w;
  }
  block_reduce2(s, s2, sbuf);
  if (threadIdx.x == 0) { part[blockIdx.x * 2] = s; part[blockIdx.x * 2 + 1] = s2; }
}

// ---------------- GN1 apply + bf16 chunk pack -----------------------------
// xnB layout: [n][16 cc][4096 t][8 c] bf16
__global__ __launch_bounds__(256)
void gn1_pack(const float* __restrict__ x, const float* __restrict__ part,
              const float* __restrict__ sc, const float* __restrict__ of,
              unsigned short* __restrict__ xnB) {
  int cc = blockIdx.x, ts = blockIdx.y, n = blockIdx.z;
  int ng = n * 16 + cc;
  float s = 0.f, s2 = 0.f;
  #pragma unroll
  for (int p = 0; p < 8; p++) { s += part[(ng*8+p)*2]; s2 += part[(ng*8+p)*2+1]; }
  float mu = s * (1.0f / 32768.0f);
  float rinv = rsqrtf(s2 * (1.0f / 32768.0f) - mu * mu + cEPS);
  int t = ts * 256 + threadIdx.x;
  float v[8];
  #pragma unroll
  for (int j = 0; j < 8; j++) {
    int c = cc * 8 + j;
    float a = rinv * sc[c];
    float bo = of[c] - mu * a;
    v[j] = x[((size_t)n * cC + c) * cHW + t] * a + bo;
  }
  unsigned pk[4];
  #pragma unroll
  for (int j = 0; j < 4; j++) pk[j] = pack2bf(v[2*j], v[2*j+1]);
  ((uint4*)xnB)[(size_t)(n * 16 + cc) * cHW + t] = make_uint4(pk[0], pk[1], pk[2], pk[3]);
}

// ---------------- QKV projection (MFMA) — R3-proven form ------------------
// grid (64 tt, 12 dg, 2 n), block 256 (4 waves x 16 t-rows)
__global__ __launch_bounds__(256)
void qkv_mfma(const unsigned short* __restrict__ xnB, const unsigned short* __restrict__ wqT,
              const float* __restrict__ bq, unsigned* __restrict__ qB,
              unsigned* __restrict__ kB, unsigned* __restrict__ vI) {
  __shared__ float vbuf[64 * 36];
  const int L = threadIdx.x & 63, w = threadIdx.x >> 6;
  const int c16 = L & 15, q = L >> 4;
  const int t0 = blockIdx.x * 64, dg = blockIdx.y, n = blockIdx.z;
  const int nh = n * 4 + (dg & 3), d0 = dg * 32;
  const f4 zf = {0.f, 0.f, 0.f, 0.f};
  f4 acc0 = zf, acc1 = zf;
  const int trow = t0 + w * 16 + c16;
  #pragma unroll
  for (int ks = 0; ks < 4; ks++) {
    bh8 a  = *(const bh8*)(xnB + ((size_t)(n * 16 + ks * 4 + q) * cHW + trow) * 8);
    bh8 b0 = *(const bh8*)(wqT + (size_t)(d0 + c16) * 128 + ks * 32 + q * 8);
    bh8 b1 = *(const bh8*)(wqT + (size_t)(d0 + 16 + c16) * 128 + ks * 32 + q * 8);
    acc0 = __builtin_amdgcn_mfma_f32_16x16x32_bf16(a, b0, acc0, 0, 0, 0);
    acc1 = __builtin_amdgcn_mfma_f32_16x16x32_bf16(a, b1, acc1, 0, 0, 0);
  }
  float blo = bq[d0 + c16], bhi = bq[d0 + 16 + c16];
  if (dg < 8) {
    float scl = (dg < 4) ? cQS : 1.0f;
    unsigned* dst = (dg < 4) ? qB : kB;
    #pragma unroll
    for (int r = 0; r < 4; r++) {
      unsigned pk = pack2bf((acc0[r] + blo) * scl, (acc1[r] + bhi) * scl);
      dst[((size_t)nh * cHW + t0 + w * 16 + q * 4 + r) * 16 + c16] = pk;
    }
  } else {
    #pragma unroll
    for (int r = 0; r < 4; r++) {
      vbuf[(w * 16 + q * 4 + r) * 36 + c16]      = acc0[r] + blo;
      vbuf[(w * 16 + q * 4 + r) * 36 + 16 + c16] = acc1[r] + bhi;
    }
    __syncthreads();
    int t16 = threadIdx.x & 15, dh8 = (threadIdx.x >> 4) & 15;
    #pragma unroll
    for (int blk = 0; blk < 2; blk++)
      #pragma unroll
      for (int hh = 0; hh < 2; hh++) {
        int dh = dh8 + hh * 16;
        float lo = vbuf[(blk * 32 + t16) * 36 + dh];
        float hi = vbuf[(blk * 32 + 16 + t16) * 36 + dh];
        vI[((size_t)nh * 32 + dh) * 2048 + (size_t)(t0 / 32 + blk) * 16 + t16] = pack2bf(lo, hi);
      }
  }
}

// ---------------- MFMA flash attention, no-max softmax (split-K) ----------
// block = 256 (4 independent waves, per-wave LDS region, no syncthreads).
// Wave owns 32 q-rows. grid (32 qb, 8 nh, SPLIT). VGPR target <= 64.
__global__ __launch_bounds__(256)
void flash_mfma(const unsigned short* __restrict__ qB,
                const unsigned short* __restrict__ kB,
                const unsigned short* __restrict__ vI,
                unsigned* __restrict__ opart, float* __restrict__ lpart) {
  __shared__ float pbuf[4][1280];   // per-wave: 4 bufs x 16 rows x stride 20
  const int w = threadIdx.x >> 6, L = threadIdx.x & 63;
  const int c16 = L & 15, q = L >> 4;
  const int qt = blockIdx.x * 4 + w, nh = blockIdx.y, ph = blockIdx.z;
  float* pb = pbuf[w];
  const f4 zf = {0.f, 0.f, 0.f, 0.f};
  const short oneb = 0x3F80;        // bf16 1.0
  const bh8 ones = {oneb, oneb, oneb, oneb, oneb, oneb, oneb, oneb};

  const unsigned short* qb = qB + ((size_t)nh * cHW + qt * 32) * cDH;
  bh8 qa[2];
  qa[0] = *(const bh8*)(qb + (size_t)c16 * cDH + q * 8);
  qa[1] = *(const bh8*)(qb + (size_t)(16 + c16) * cDH + q * 8);

  f4 o[2][2] = {{zf, zf}, {zf, zf}};
  f4 lacc[2] = {zf, zf};            // row-sums of truncated P via MFMA(P, ones)

  const unsigned short* kb = kB + (size_t)nh * cHW * cDH;
  const unsigned short* vb = vI + (size_t)nh * cDH * cHW;

  const int kbeg = ph * (cHW / SPLIT);
  const int kend = kbeg + cHW / SPLIT;

  for (int kt = kbeg; kt < kend; kt += 64) {
    bh8 kf[4];
    #pragma unroll
    for (int s = 0; s < 4; s++)
      kf[s] = *(const bh8*)(kb + (size_t)(kt + s*16 + c16) * cDH + q * 8);
    bh8 vf[2][2];
    #pragma unroll
    for (int ks = 0; ks < 2; ks++)
      #pragma unroll
      for (int dt = 0; dt < 2; dt++)
        vf[ks][dt] = *(const bh8*)(vb + (size_t)(dt*16 + c16) * cHW + kt + ks*32 + q*8);

    f4 sf[2][4];
    #pragma unroll
    for (int rt = 0; rt < 2; rt++)
      #pragma unroll
      for (int s = 0; s < 4; s++)
        sf[rt][s] = __builtin_amdgcn_mfma_f32_16x16x32_bf16(qa[rt], kf[s], zf, 0, 0, 0);

    // exp2 (fixed max 0) + truncating pack -> LDS (P in A-frag pair order)
    #pragma unroll
    for (int rt = 0; rt < 2; rt++) {
      #pragma unroll
      for (int s = 0; s < 4; s++)
        #pragma unroll
        for (int r = 0; r < 4; r++)
          sf[rt][s][r] = __builtin_amdgcn_exp2f(sf[rt][s][r]);
      #pragma unroll
      for (int st = 0; st < 2; st++)
        #pragma unroll
        for (int r = 0; r < 4; r++) {
          unsigned pk = pack_trunc(sf[rt][2*st][r], sf[rt][2*st+1][r]);
          pb[(rt*2 + st)*320 + (q*4 + r)*20 + c16] = __builtin_bit_cast(float, pk);
        }
    }
    // P x V -> O ; P x ones -> l (all on MFMA pipe)
    #pragma unroll
    for (int rt = 0; rt < 2; rt++)
      #pragma unroll
      for (int st = 0; st < 2; st++) {
        bh8 pa = *(const bh8*)(pb + (rt*2 + st)*320 + c16*20 + q*4);
        o[rt][0] = __builtin_amdgcn_mfma_f32_16x16x32_bf16(pa, vf[st][0], o[rt][0], 0, 0, 0);
        o[rt][1] = __builtin_amdgcn_mfma_f32_16x16x32_bf16(pa, vf[st][1], o[rt][1], 0, 0, 0);
        lacc[rt] = __builtin_amdgcn_mfma_f32_16x16x32_bf16(pa, ones, lacc[rt], 0, 0, 0);
      }
  }

  // epilogue: lacc already holds full row sums in every lane (all-ones B)
  size_t base_r = (size_t)ph * 32768 + (size_t)nh * cHW + (size_t)qt * 32;
  #pragma unroll
  for (int rt = 0; rt < 2; rt++)
    #pragma unroll
    for (int r = 0; r < 4; r++) {
      size_t rr = base_r + rt*16 + q*4 + r;
      if (c16 == 0) lpart[rr] = lacc[rt][r];
      opart[rr * 16 + c16] = pack_trunc(o[rt][0][r], o[rt][1][r]);
    }
}

// ---------------- split-K combine -> yB bf16 [row][32] --------------------
// grid 128, block 256; one thread per row
__global__ __launch_bounds__(256)
void combine(const unsigned* __restrict__ opart, const float* __restrict__ lpart,
             unsigned* __restrict__ yB) {
  size_t r = (size_t)blockIdx.x * 256 + threadIdx.x;
  float l = 0.f;
  #pragma unroll
  for (int p = 0; p < SPLIT; p++) l += lpart[(size_t)p * 32768 + r];
  float e[32];
  #pragma unroll
  for (int j = 0; j < 32; j++) e[j] = 0.f;
  #pragma unroll
  for (int p = 0; p < SPLIT; p++) {
    const uint4* op = (const uint4*)(opart + ((size_t)p * 32768 + r) * 16);
    #pragma unroll
    for (int j = 0; j < 4; j++) {
      uint4 v = op[j];
      e[j*4+0] += bflo(v.x); e[16+j*4+0] += bfhi(v.x);
      e[j*4+1] += bflo(v.y); e[16+j*4+1] += bfhi(v.y);
      e[j*4+2] += bflo(v.z); e[16+j*4+2] += bfhi(v.z);
      e[j*4+3] += bflo(v.w); e[16+j*4+3] += bfhi(v.w);
    }
  }
  float inv = 1.0f / l;
  unsigned pk[16];
  #pragma unroll
  for (int m = 0; m < 16; m++) pk[m] = pack2bf(e[2*m] * inv, e[2*m+1] * inv);
  uint4* dst = (uint4*)(yB + r * 16);
  #pragma unroll
  for (int j = 0; j < 4; j++)
    dst[j] = make_uint4(pk[4*j], pk[4*j+1], pk[4*j+2], pk[4*j+3]);
}

// ---------------- out projection (MFMA) -> proj fp32 [n][c][t] ------------
// grid (64 tt, 4 dg, 2 n), block 256 — R3-proven form
__global__ __launch_bounds__(256)
void out_mfma(const unsigned short* __restrict__ yB, const unsigned short* __restrict__ woT,
              const float* __restrict__ bo, float* __restrict__ proj) {
  __shared__ float obuf[64 * 36];
  const int L = threadIdx.x & 63, w = threadIdx.x >> 6;
  const int c16 = L & 15, q = L >> 4;
  const int t0 = blockIdx.x * 64, d0 = blockIdx.y * 32, n = blockIdx.z;
  const f4 zf = {0.f, 0.f, 0.f, 0.f};
  f4 acc0 = zf, acc1 = zf;
  const int trow = t0 + w * 16 + c16;
  #pragma unroll
  for (int h = 0; h < 4; h++) {
    bh8 a  = *(const bh8*)(yB + ((size_t)(n * 4 + h) * cHW + trow) * 32 + q * 8);
    bh8 b0 = *(const bh8*)(woT + (size_t)(d0 + c16) * 128 + h * 32 + q * 8);
    bh8 b1 = *(const bh8*)(woT + (size_t)(d0 + 16 + c16) * 128 + h * 32 + q * 8);
    acc0 = __builtin_amdgcn_mfma_f32_16x16x32_bf16(a, b0, acc0, 0, 0, 0);
    acc1 = __builtin_amdgcn_mfma_f32_16x16x32_bf16(a, b1, acc1, 0, 0, 0);
  }
  float blo = bo[d0 + c16], bhi = bo[d0 + 16 + c16];
  #pragma unroll
  for (int r = 0; r < 4; r++) {
    obuf[(w * 16 + q * 4 + r) * 36 + c16]      = acc0[r] + blo;
    obuf[(w * 16 + q * 4 + r) * 36 + 16 + c16] = acc1[r] + bhi;
  }
  __syncthreads();
  int t16 = threadIdx.x & 15, d8 = (threadIdx.x >> 4) & 15;
  #pragma unroll
  for (int tc = 0; tc < 4; tc++)
    #pragma unroll
    for (int hh = 0; hh < 2; hh++) {
      int d = d8 + hh * 16;
      proj[((size_t)n * cC + d0 + d) * cHW + t0 + tc * 16 + t16] =
          obuf[(tc * 16 + t16) * 36 + d];
    }
}

// ---------------- GN2 apply + residual (recomputes xn from x) -------------
__global__ __launch_bounds__(256)
void gn2_apply(const float* __restrict__ x, const float* __restrict__ proj,
               const float* __restrict__ p1, const float* __restrict__ p2,
               const float* __restrict__ s1, const float* __restrict__ o1,
               const float* __restrict__ s2, const float* __restrict__ o2,
               float* __restrict__ out) {
  int tid = blockIdx.x * 256 + threadIdx.x;
  int Cg = tid >> 8;
  int n = Cg >> 7, ch = Cg & 127, g = ch >> 3, ng = n * 16 + g;
  float sa = 0.f, sb = 0.f, ta = 0.f, tb = 0.f;
  #pragma unroll
  for (int p = 0; p < 8; p++) {
    sa += p1[(ng*8+p)*2]; sb += p1[(ng*8+p)*2+1];
    ta += p2[(ng*8+p)*2]; tb += p2[(ng*8+p)*2+1];
  }
  float mu1 = sa * (1.0f/32768.0f);
  float ri1 = rsqrtf(sb * (1.0f/32768.0f) - mu1*mu1 + cEPS);
  float a1 = ri1 * s1[ch], b1 = o1[ch] - mu1 * a1;
  float mu2 = ta * (1.0f/32768.0f);
  float ri2 = rsqrtf(tb * (1.0f/32768.0f) - mu2*mu2 + cEPS);
  float a2 = ri2 * s2[ch], b2 = o2[ch] - mu2 * a2;
  const float4* x4 = (const float4*)x;
  const float4* pr4 = (const float4*)proj;
  float4* o4 = (float4*)out;
  #pragma unroll
  for (int i = 0; i < 4; i++) {
    size_t f = (size_t)tid * 4 + i;
    float4 xv = x4[f], pv = pr4[f];
    float4 r;
    r.x = xv.x * a1 + b1 + pv.x * a2 + b2;
    r.y = xv.y * a1 + b1 + pv.y * a2 + b2;
    r.z = xv.z * a1 + b1 + pv.z * a2 + b2;
    r.w = xv.w * a1 + b1 + pv.w * a2 + b2;
    o4[f] = r;
  }
}

// ---------------- launcher ------------------------------------------------
extern "C" void kernel_launch(void* const* d_in, const int* in_sizes, int n_in,
                              void* d_out, int out_size, void* d_ws, size_t ws_size,
                              hipStream_t stream) {
  const float* x     = (const float*)d_in[0];
  const float* w_qkv = (const float*)d_in[1];
  const float* b_qkv = (const float*)d_in[2];
  const float* w_out = (const float*)d_in[3];
  const float* b_out = (const float*)d_in[4];
  const float* g1s   = (const float*)d_in[5];
  const float* g1o   = (const float*)d_in[6];
  const float* g2s   = (const float*)d_in[7];
  const float* g2o   = (const float*)d_in[8];
  float* out = (float*)d_out;
  float* ws  = (float*)d_ws;

  const size_t MAP = (size_t)2 * cC * cHW;            // 1,048,576 elems
  float* proj    = ws;                                // 4 MB
  float* lpart   = proj + MAP;                        // SPLIT*32768 fl
  float* stats1  = lpart + (size_t)SPLIT * 32768;     // 512 fl
  float* stats2  = stats1 + 512;                      // 512 fl
  unsigned* opart = (unsigned*)(stats2 + 512);        // SPLIT*32768*16 u32 = 8 MB
  unsigned* qB   = opart + (size_t)SPLIT * 32768 * 16;  // 2 MB
  unsigned* kB   = qB + MAP / 2;                      // 2 MB
  unsigned* vI   = kB + MAP / 2;                      // 2 MB
  unsigned* yB   = vI + MAP / 2;                      // 2 MB
  unsigned short* xnB = (unsigned short*)(yB + MAP / 2);  // 2 MB
  unsigned short* wqT = xnB + MAP;                    // 96 KB
  unsigned short* woT = wqT + 49152;                  // 32 KB

  prep      <<<dim3(272),           256, 0, stream>>>(x, stats1, w_qkv, w_out, wqT, woT);
  gn1_pack  <<<dim3(16, 16, 2),     256, 0, stream>>>(x, stats1, g1s, g1o, xnB);
  qkv_mfma  <<<dim3(64, 12, 2),     256, 0, stream>>>(xnB, wqT, b_qkv, qB, kB, vI);
  flash_mfma<<<dim3(32, 8, SPLIT),  256, 0, stream>>>((const unsigned short*)qB,
                                                      (const unsigned short*)kB,
                                                      (const unsigned short*)vI,
                                                      opart, lpart);
  combine   <<<dim3(128),           256, 0, stream>>>(opart, lpart, yB);
  out_mfma  <<<dim3(64, 4, 2),      256, 0, stream>>>((const unsigned short*)yB, woT,
                                                      b_out, proj);
  gn_stats  <<<dim3(256),           256, 0, stream>>>(proj, stats2);
  gn2_apply <<<dim3(256),           256, 0, stream>>>(x, proj, stats1, stats2,
                                                      g1s, g1o, g2s, g2o, out);
}